// Round 8
// baseline (384.624 us; speedup 1.0000x reference)
//
#include <hip/hip_runtime.h>
#include <math.h>

// FairFightConvQAT: 4-layer fake-quantized CNN forward, fp32 in/out.
// Intermediates: int8 NHWC. L2/L3 use exact-integer i8 MFMA (16x16x64).
// L1: conv3x3 1->16 +relu   (VALU, fp32 in, int8 NHWC out, 2 passes)
// L2: conv3x3 16->16 +relu  (i8 MFMA, NHWC, 2 passes: absmax then store)
// L3: conv3x3 16->16 +relu  (i8 MFMA, 2 passes)
// L4: conv2x2 16->1 +sigmoid (VALU, NHWC in, fp32 out, 1 pass, no LDS)
//
// Exactness: q_x in [0,127], q_w in [-128,127]; i8 MFMA accumulates
// sum(q_x*q_w) exactly in i32 (|acc| <= 2.3e6 < 2^24, exact in f32 too).
// Requant uses true division rintf(y/s) to mirror the reference.
//
// ws layout: [0,32) 8 absmax slots (0..3 = x,h1,h2,h3; 4..7 = w1..w4)
//   256: qw1 (f32 [pos][co], 576B) | 1024: qw4 (f32, 256B)
//   2048: wi8_2 | 5120: wi8_3  (i8 MFMA A-fragments, 3 K=64 groups, 3KB each)
//   32768: qb1 (h1, 65,028,096B; later reused for h3)
//   32768+Q1: qb2 (h2, 62,980,096B)                total ~128.06 MB

#define THREADS 256

typedef __attribute__((ext_vector_type(4))) int i32x4;

// grids are multiples of 8 -> bijective; groups each image's 16 tiles on one
// XCD so its ~254KB NHWC activation stays L2-resident.
__device__ __forceinline__ int xcd_swz(int bid, int nwg) {
    return (bid & 7) * (nwg >> 3) + (bid >> 3);
}

__device__ __forceinline__ float block_reduce_max(float m, float* wred) {
#pragma unroll
    for (int off = 32; off > 0; off >>= 1)
        m = fmaxf(m, __shfl_down(m, off, 64));
    if ((threadIdx.x & 63) == 0) wred[threadIdx.x >> 6] = m;
    __syncthreads();
    return fmaxf(fmaxf(wred[0], wred[1]), fmaxf(wred[2], wred[3]));
}

__global__ void init_kernel(unsigned int* slots) {
    if (threadIdx.x < 8) slots[threadIdx.x] = 0u;
}

__global__ void fill_kernel(float* out, int n, float v) {
    int i = blockIdx.x * blockDim.x + threadIdx.x;
    int stride = gridDim.x * blockDim.x;
    for (; i < n; i += stride) out[i] = v;
}

__global__ __launch_bounds__(THREADS) void absmax4_kernel(
    const float4* __restrict__ x, int n4, unsigned int* __restrict__ slot) {
    __shared__ float wred[4];
    float m = 0.f;
    const int stride = gridDim.x * blockDim.x;
    for (int i = blockIdx.x * blockDim.x + threadIdx.x; i < n4; i += stride) {
        float4 v = x[i];
        m = fmaxf(fmaxf(fabsf(v.x), fabsf(v.y)),
                  fmaxf(fmaxf(fabsf(v.z), fabsf(v.w)), m));
    }
    m = block_reduce_max(m, wred);
    if (threadIdx.x == 0) atomicMax(slot, __float_as_uint(m));
}

// One block per weight tensor: absmax -> fake-quant.
// b0: qw1 f32 [pos][co]; b3: qw4 f32 identity order; b1/b2: wi8 int8 MFMA
// A-fragments: i = g*1024 + lane*16 + ci; co=lane&15, qq=lane>>4, pos=4g+qq.
__global__ __launch_bounds__(THREADS) void quant_w_kernel(
    const float* __restrict__ w1, const float* __restrict__ w2,
    const float* __restrict__ w3, const float* __restrict__ w4,
    float* __restrict__ qw1, float* __restrict__ qw4,
    signed char* __restrict__ wi8_2, signed char* __restrict__ wi8_3,
    unsigned int* __restrict__ slots) {
    __shared__ float wred[4];
    const float* w; int nel;
    switch (blockIdx.x) {
        case 0:  w = w1; nel = 144;  break;
        case 1:  w = w2; nel = 2304; break;
        case 2:  w = w3; nel = 2304; break;
        default: w = w4; nel = 64;   break;
    }
    float m = 0.f;
    for (int i = threadIdx.x; i < nel; i += blockDim.x)
        m = fmaxf(m, fabsf(w[i]));
    m = block_reduce_max(m, wred);
    if (threadIdx.x == 0) slots[4 + blockIdx.x] = __float_as_uint(m);
    const float s = fmaxf(m, 1e-8f) / 127.0f;

    if (blockIdx.x == 0) {
        for (int i = threadIdx.x; i < 144; i += blockDim.x) {
            int p = i % 9, o = i / 9;   // w1 [o][0][ky][kx]
            float q = fminf(fmaxf(rintf(w[i] / s), -128.f), 127.f);
            qw1[p * 16 + o] = q * s;
        }
    } else if (blockIdx.x == 3) {
        for (int i = threadIdx.x; i < 64; i += blockDim.x) {
            float q = fminf(fmaxf(rintf(w[i] / s), -128.f), 127.f);
            qw4[i] = q * s;             // [ci][ky][kx] identity
        }
    } else {
        signed char* wi8 = (blockIdx.x == 1) ? wi8_2 : wi8_3;
        for (int i = threadIdx.x; i < 3072; i += blockDim.x) {
            int ci = i & 15, lane = (i >> 4) & 63, g = i >> 10;
            int co = lane & 15, qq = lane >> 4;
            int pos = 4 * g + qq;
            float v = 0.f;
            if (pos < 9) {
                int ky = pos / 3, kx = pos % 3;
                v = fminf(fmaxf(rintf(w[((co * 16 + ci) * 3 + ky) * 3 + kx] / s),
                                -128.f), 127.f);
            }
            wi8[i] = (signed char)(int)v;
        }
    }
}

// ------------- L1: 1->16 conv3x3 (VALU), fp32 -> int8 NHWC, 32x32 tile -----
template <int MODE>   // 1 = relu+absmax only; 2 = relu + int8 NHWC store
__global__ __launch_bounds__(THREADS) void conv1_kernel(
    const float* __restrict__ x, const float* __restrict__ qw,
    const float* __restrict__ bias, signed char* __restrict__ out,
    unsigned int* __restrict__ slots) {
    constexpr int IH = 128, IW = 128, OH = 126, OW = 126;
    __shared__ float tile[34 * 34];
    __shared__ float wred[4];
    const int bid = xcd_swz(blockIdx.x, gridDim.x);
    const int n = bid >> 4, tr = bid & 15;
    const int oy0 = (tr >> 2) * 32, ox0 = (tr & 3) * 32;
    const float s_in = fmaxf(__uint_as_float(slots[0]), 1e-8f) / 127.0f;
    const float* xN = x + (size_t)n * IH * IW;

#pragma unroll
    for (int it = 0; it < 5; ++it) {
        int px = it * 256 + threadIdx.x;
        if (px < 1156) {
            int iy = px / 34, ix = px - iy * 34;
            int gy = min(oy0 + iy, IH - 1), gx = min(ox0 + ix, IW - 1);
            float q = rintf(xN[gy * IW + gx] / s_in);  // exact div, as reference
            tile[px] = fminf(fmaxf(q, -128.f), 127.f);
        }
    }
    __syncthreads();

    const int tx = (threadIdx.x & 15) * 2, ty = (threadIdx.x >> 4) * 2;
    float m = 0.f;
    float s_out = 0.f;
    if constexpr (MODE == 2)
        s_out = fmaxf(__uint_as_float(slots[1]), 1e-8f) / 127.0f;

#pragma unroll
    for (int sy = 0; sy < 2; ++sy)
#pragma unroll
    for (int sx = 0; sx < 2; ++sx) {
        const int py = ty + sy, pxx = tx + sx;
        float acc[16];
#pragma unroll
        for (int c = 0; c < 16; ++c) acc[c] = 0.f;
#pragma unroll
        for (int p = 0; p < 9; ++p) {
            const float xv = tile[(py + p / 3) * 34 + pxx + p % 3];
            const float* wp = qw + p * 16;
#pragma unroll
            for (int co = 0; co < 16; ++co)
                acc[co] = fmaf(xv, wp[co], acc[co]);
        }
        const int oy = oy0 + py, ox = ox0 + pxx;
        const bool ok = (oy < OH) && (ox < OW);
        if constexpr (MODE == 1) {
#pragma unroll
            for (int co = 0; co < 16; ++co) {
                float y = fmaxf(fmaf(acc[co], s_in, bias[co]), 0.f);
                if (ok) m = fmaxf(m, y);
            }
        } else {
            unsigned pk[4] = {0u, 0u, 0u, 0u};
#pragma unroll
            for (int co = 0; co < 16; ++co) {
                float y = fmaxf(fmaf(acc[co], s_in, bias[co]), 0.f);
                float q8 = fminf(fmaxf(rintf(y / s_out), -128.f), 127.f);
                pk[co >> 2] |= ((unsigned)(int)q8 & 0xffu) << ((co & 3) * 8);
            }
            if (ok) {
                int4 v; v.x = pk[0]; v.y = pk[1]; v.z = pk[2]; v.w = pk[3];
                *(int4*)(out + ((size_t)(n * OH + oy) * OW + ox) * 16) = v;
            }
        }
    }
    if constexpr (MODE == 1) {
        m = block_reduce_max(m, wred);
        if (threadIdx.x == 0) atomicMax(&slots[1], __float_as_uint(m));
    }
}

// ------- L2/L3: 16->16 conv3x3, i8 MFMA 16x16x64, NHWC, 32x32 tile ---------
// Per wave: quadrant (wr,wc); 16 rows x 3 MFMAs (K=64 = 4 positions x 16ch;
// positions 9..11 zero-weight pad). B frag = one pixel's 16ch = ds_read_b128.
template <bool STORE>
__global__ __launch_bounds__(THREADS) void mconv_kernel(
    const signed char* __restrict__ in, const signed char* __restrict__ wi8,
    const float* __restrict__ bias, signed char* __restrict__ out,
    unsigned int* __restrict__ slots, int in_slot, int w_slot, int out_slot,
    int IH, int IW) {
    __shared__ signed char tile[1156 * 16];   // 34x34 px, 16B each
    __shared__ float wred[4];
    const int OH = IH - 2, OW = IW - 2;
    const int bid = xcd_swz(blockIdx.x, gridDim.x);
    const int n = bid >> 4, tr = bid & 15;
    const int oy0 = (tr >> 2) * 32, ox0 = (tr & 3) * 32;

    const int tid = threadIdx.x, lane = tid & 63, wv = tid >> 6;
    const int q = lane >> 4, col = lane & 15;

    const signed char* inN = in + (size_t)n * IH * IW * 16;

    // staging: pure int8 copy, no conversion
#pragma unroll
    for (int it = 0; it < 5; ++it) {
        int px = it * 256 + tid;
        if (px < 1156) {
            int iy = px / 34, ix = px - iy * 34;
            int gy = min(oy0 + iy, IH - 1), gx = min(ox0 + ix, IW - 1);
            *(int4*)(tile + px * 16) =
                *(const int4*)(inN + ((size_t)gy * IW + gx) * 16);
        }
    }

    i32x4 afrag[3];
#pragma unroll
    for (int g = 0; g < 3; ++g)
        afrag[g] = ((const i32x4*)wi8)[g * 64 + lane];

    __syncthreads();

    int poff[3];
#pragma unroll
    for (int g = 0; g < 3; ++g) {
        int pos = 4 * g + q;
        int dy = (pos < 9) ? pos / 3 : 0;
        int dx = (pos < 9) ? pos % 3 : 0;   // pad reads valid px; weight = 0
        poff[g] = (dy * 34 + dx) * 16;
    }
    const int wr = wv >> 1, wc = wv & 1;
    const int bx = 16 * wc + col;
    const int ox = ox0 + bx;

    const float s_in = fmaxf(__uint_as_float(slots[in_slot]), 1e-8f) / 127.0f;
    const float s_w  = fmaxf(__uint_as_float(slots[w_slot]),  1e-8f) / 127.0f;
    const float sxw = s_in * s_w;
    float bj[4];
#pragma unroll
    for (int j = 0; j < 4; ++j) bj[j] = bias[q * 4 + j];
    float s_out = 0.f;
    if constexpr (STORE)
        s_out = fmaxf(__uint_as_float(slots[out_slot]), 1e-8f) / 127.0f;

    signed char* outN = out + (size_t)n * OH * OW * 16;
    float m = 0.f;

#pragma unroll 4
    for (int r = 0; r < 16; ++r) {
        const int iy = 16 * wr + r;
        const int base = (iy * 34 + bx) * 16;
        i32x4 acc = {0, 0, 0, 0};
#pragma unroll
        for (int g = 0; g < 3; ++g) {
            i32x4 b = *(const i32x4*)(tile + base + poff[g]);
            acc = __builtin_amdgcn_mfma_i32_16x16x64_i8(afrag[g], b, acc, 0, 0, 0);
        }
        const int oy = oy0 + iy;
        const bool ok = (oy < OH) && (ox < OW);
        if constexpr (STORE) {
            unsigned pk = 0u;
#pragma unroll
            for (int j = 0; j < 4; ++j) {
                float y = fmaxf(fmaf((float)acc[j], sxw, bj[j]), 0.f);
                float q8 = fminf(fmaxf(rintf(y / s_out), -128.f), 127.f);
                pk |= ((unsigned)(int)q8 & 0xffu) << (j * 8);
            }
            if (ok)
                *(unsigned*)(outN + ((size_t)oy * OW + ox) * 16 + q * 4) = pk;
        } else {
#pragma unroll
            for (int j = 0; j < 4; ++j) {
                float y = fmaxf(fmaf((float)acc[j], sxw, bj[j]), 0.f);
                if (ok) m = fmaxf(m, y);
            }
        }
    }
    if constexpr (!STORE) {
        m = block_reduce_max(m, wred);
        if (tid == 0) atomicMax(&slots[out_slot], __float_as_uint(m));
    }
}

// ---------------- L4: 16->1 conv2x2 + sigmoid, NHWC in, fp32 out -----------
__global__ __launch_bounds__(THREADS) void conv4_kernel(
    const signed char* __restrict__ in, const float* __restrict__ qw,
    const float* __restrict__ bias, float* __restrict__ out,
    unsigned int* __restrict__ slots) {
    constexpr int IH = 122, IW = 122, OH = 121, OW = 121;
    const int bid = xcd_swz(blockIdx.x, gridDim.x);
    const int n = bid >> 4, tr = bid & 15;
    const int oyb = (tr >> 2) * 32 + ((threadIdx.x >> 4) * 2);
    const int oxb = (tr & 3) * 32 + ((threadIdx.x & 15) * 2);
    const float s_in = fmaxf(__uint_as_float(slots[3]), 1e-8f) / 127.0f;
    const float b0 = bias[0];
    const signed char* inN = in + (size_t)n * IH * IW * 16;

    float w[64];
#pragma unroll
    for (int i = 0; i < 64; ++i) w[i] = qw[i];  // wave-uniform -> scalar regs

#pragma unroll
    for (int sy = 0; sy < 2; ++sy)
#pragma unroll
    for (int sx = 0; sx < 2; ++sx) {
        const int oy = oyb + sy, ox = oxb + sx;
        if (oy >= OH || ox >= OW) continue;
        float acc = 0.f;
#pragma unroll
        for (int ky = 0; ky < 2; ++ky)
#pragma unroll
        for (int kx = 0; kx < 2; ++kx) {
            union { int4 v; signed char c[16]; } u;
            u.v = *(const int4*)(inN + ((size_t)(oy + ky) * IW + ox + kx) * 16);
#pragma unroll
            for (int ci = 0; ci < 16; ++ci)
                acc = fmaf((float)u.c[ci], w[(ci * 2 + ky) * 2 + kx], acc);
        }
        float y = fmaf(acc, s_in, b0);
        out[(size_t)(n * OH + oy) * OW + ox] = 1.0f / (1.0f + expf(-y));
    }
}

extern "C" void kernel_launch(void* const* d_in, const int* in_sizes, int n_in,
                              void* d_out, int out_size, void* d_ws, size_t ws_size,
                              hipStream_t stream) {
    (void)in_sizes; (void)n_in;
    const float* x  = (const float*)d_in[0];
    const float* w1 = (const float*)d_in[1];
    const float* b1 = (const float*)d_in[2];
    const float* w2 = (const float*)d_in[3];
    const float* b2 = (const float*)d_in[4];
    const float* w3 = (const float*)d_in[5];
    const float* b3 = (const float*)d_in[6];
    const float* w4 = (const float*)d_in[7];
    const float* b4 = (const float*)d_in[8];

    char* ws = (char*)d_ws;
    unsigned int* slots = (unsigned int*)ws;
    float* qw1 = (float*)(ws + 256);
    float* qw4 = (float*)(ws + 1024);
    signed char* wi8_2 = (signed char*)(ws + 2048);
    signed char* wi8_3 = (signed char*)(ws + 5120);

    const size_t Q1 = 65028096ULL;   // 256*126*126*16 int8 (h1; later h3)
    const size_t Q2 = 62980096ULL;   // 256*124*124*16 int8 (h2)
    signed char* qb1 = (signed char*)(ws + 32768);
    signed char* qb2 = (signed char*)(ws + 32768 + Q1);
    float* outp = (float*)d_out;

    const size_t need = 32768ULL + Q1 + Q2;  // ~128.06 MB
    if (ws_size < need) {
        float v = 100.0f + (float)(ws_size >> 20);
        hipLaunchKernelGGL(fill_kernel, dim3(1024), dim3(THREADS), 0, stream,
                           outp, out_size, v);
        return;
    }

    const int blocks = 256 * 16;  // 4096 = N * 16 tiles of 32x32; %8==0

    hipLaunchKernelGGL(init_kernel, dim3(1), dim3(64), 0, stream, slots);
    hipLaunchKernelGGL(absmax4_kernel, dim3(2048), dim3(THREADS), 0, stream,
                       (const float4*)x, 256 * 128 * 128 / 4, slots + 0);
    hipLaunchKernelGGL(quant_w_kernel, dim3(4), dim3(THREADS), 0, stream,
                       w1, w2, w3, w4, qw1, qw4, wi8_2, wi8_3, slots);

    // L1: fp32 x -> int8 h1 (NHWC), two passes
    hipLaunchKernelGGL((conv1_kernel<1>), dim3(blocks), dim3(THREADS), 0, stream,
                       x, qw1, b1, nullptr, slots);
    hipLaunchKernelGGL((conv1_kernel<2>), dim3(blocks), dim3(THREADS), 0, stream,
                       x, qw1, b1, qb1, slots);
    // L2 (i8 MFMA): h1 -> h2, two passes
    hipLaunchKernelGGL((mconv_kernel<false>), dim3(blocks), dim3(THREADS), 0, stream,
                       qb1, wi8_2, b2, nullptr, slots, 1, 5, 2, 126, 126);
    hipLaunchKernelGGL((mconv_kernel<true>), dim3(blocks), dim3(THREADS), 0, stream,
                       qb1, wi8_2, b2, qb2, slots, 1, 5, 2, 126, 126);
    // L3 (i8 MFMA): h2 -> h3 (reuses qb1), two passes
    hipLaunchKernelGGL((mconv_kernel<false>), dim3(blocks), dim3(THREADS), 0, stream,
                       qb2, wi8_3, b3, nullptr, slots, 2, 6, 3, 124, 124);
    hipLaunchKernelGGL((mconv_kernel<true>), dim3(blocks), dim3(THREADS), 0, stream,
                       qb2, wi8_3, b3, qb1, slots, 2, 6, 3, 124, 124);
    // L4: h3 -> fp32 out, sigmoid, single pass
    hipLaunchKernelGGL(conv4_kernel, dim3(blocks), dim3(THREADS), 0, stream,
                       qb1, qw4, b4, outp, slots);
}

// Round 9
// 333.463 us; speedup vs baseline: 1.1534x; 1.1534x over previous
//
#include <hip/hip_runtime.h>
#include <math.h>

// FairFightConvQAT: 4-layer fake-quantized CNN forward, fp32 in/out.
// Intermediates: int8 NHWC. L2/L3 use exact-integer i8 MFMA (16x16x64).
// L1: conv3x3 1->16 +relu   (VALU, fp32 in, int8 NHWC out, 2 passes)
// L2: conv3x3 16->16 +relu  (i8 MFMA, NHWC, 2 passes: absmax then store)
// L3: conv3x3 16->16 +relu  (i8 MFMA, 2 passes)
// L4: conv2x2 16->1 +sigmoid (VALU, NHWC in, fp32 out, 1 pass, no LDS)
//
// Exactness: q_x in [0,127], q_w in [-128,127]; i8 MFMA accumulates
// sum(q_x*q_w) exactly in i32 (|acc| <= 2.3e6 < 2^24, exact in f32 too).
// Requant uses y * (127/absmax) -- proven equivalent-in-threshold (round 3).
//
// ws layout: [0,32) 8 absmax slots (0..3 = x,h1,h2,h3; 4..7 = w1..w4)
//   256: qw1 (f32 [pos][co], 576B) | 1024: qw4 (f32, 256B)
//   2048: wi8_2 | 5120: wi8_3  (i8 MFMA A-fragments, 3 K=64 groups, 3KB each)
//   32768: qb1 (h1, 65,028,096B; later reused for h3)
//   32768+Q1: qb2 (h2, 62,980,096B)                total ~128.06 MB

#define THREADS 256

typedef __attribute__((ext_vector_type(4))) int i32x4;

// grids are multiples of 8 -> bijective; groups each image's 16 tiles on one
// XCD so its ~254KB NHWC activation stays L2-resident.
__device__ __forceinline__ int xcd_swz(int bid, int nwg) {
    return (bid & 7) * (nwg >> 3) + (bid >> 3);
}

// LDS record swizzle: record index -> byte offset. XORs addr bits [6:4] with
// rec bits [5:3] so records i and i+8 (same bank group at stride 16) diverge.
// Bijective; applied identically on write and read.
__device__ __forceinline__ int swzb(int rec) {
    return (rec << 4) ^ ((rec & 56) << 1);
}

__device__ __forceinline__ float block_reduce_max(float m, float* wred) {
#pragma unroll
    for (int off = 32; off > 0; off >>= 1)
        m = fmaxf(m, __shfl_down(m, off, 64));
    if ((threadIdx.x & 63) == 0) wred[threadIdx.x >> 6] = m;
    __syncthreads();
    return fmaxf(fmaxf(wred[0], wred[1]), fmaxf(wred[2], wred[3]));
}

__global__ void init_kernel(unsigned int* slots) {
    if (threadIdx.x < 8) slots[threadIdx.x] = 0u;
}

__global__ void fill_kernel(float* out, int n, float v) {
    int i = blockIdx.x * blockDim.x + threadIdx.x;
    int stride = gridDim.x * blockDim.x;
    for (; i < n; i += stride) out[i] = v;
}

__global__ __launch_bounds__(THREADS) void absmax4_kernel(
    const float4* __restrict__ x, int n4, unsigned int* __restrict__ slot) {
    __shared__ float wred[4];
    float m = 0.f;
    const int stride = gridDim.x * blockDim.x;
    for (int i = blockIdx.x * blockDim.x + threadIdx.x; i < n4; i += stride) {
        float4 v = x[i];
        m = fmaxf(fmaxf(fabsf(v.x), fabsf(v.y)),
                  fmaxf(fmaxf(fabsf(v.z), fabsf(v.w)), m));
    }
    m = block_reduce_max(m, wred);
    if (threadIdx.x == 0) atomicMax(slot, __float_as_uint(m));
}

// One block per weight tensor: absmax -> fake-quant.
// b0: qw1 f32 [pos][co]; b3: qw4 f32 identity order; b1/b2: wi8 int8 MFMA
// A-fragments: i = g*1024 + lane*16 + ci; co=lane&15, qq=lane>>4, pos=4g+qq.
__global__ __launch_bounds__(THREADS) void quant_w_kernel(
    const float* __restrict__ w1, const float* __restrict__ w2,
    const float* __restrict__ w3, const float* __restrict__ w4,
    float* __restrict__ qw1, float* __restrict__ qw4,
    signed char* __restrict__ wi8_2, signed char* __restrict__ wi8_3,
    unsigned int* __restrict__ slots) {
    __shared__ float wred[4];
    const float* w; int nel;
    switch (blockIdx.x) {
        case 0:  w = w1; nel = 144;  break;
        case 1:  w = w2; nel = 2304; break;
        case 2:  w = w3; nel = 2304; break;
        default: w = w4; nel = 64;   break;
    }
    float m = 0.f;
    for (int i = threadIdx.x; i < nel; i += blockDim.x)
        m = fmaxf(m, fabsf(w[i]));
    m = block_reduce_max(m, wred);
    if (threadIdx.x == 0) slots[4 + blockIdx.x] = __float_as_uint(m);
    const float s = fmaxf(m, 1e-8f) / 127.0f;

    if (blockIdx.x == 0) {
        for (int i = threadIdx.x; i < 144; i += blockDim.x) {
            int p = i % 9, o = i / 9;   // w1 [o][0][ky][kx]
            float q = fminf(fmaxf(rintf(w[i] / s), -128.f), 127.f);
            qw1[p * 16 + o] = q * s;
        }
    } else if (blockIdx.x == 3) {
        for (int i = threadIdx.x; i < 64; i += blockDim.x) {
            float q = fminf(fmaxf(rintf(w[i] / s), -128.f), 127.f);
            qw4[i] = q * s;             // [ci][ky][kx] identity
        }
    } else {
        signed char* wi8 = (blockIdx.x == 1) ? wi8_2 : wi8_3;
        for (int i = threadIdx.x; i < 3072; i += blockDim.x) {
            int ci = i & 15, lane = (i >> 4) & 63, g = i >> 10;
            int co = lane & 15, qq = lane >> 4;
            int pos = 4 * g + qq;
            float v = 0.f;
            if (pos < 9) {
                int ky = pos / 3, kx = pos % 3;
                v = fminf(fmaxf(rintf(w[((co * 16 + ci) * 3 + ky) * 3 + kx] / s),
                                -128.f), 127.f);
            }
            wi8[i] = (signed char)(int)v;
        }
    }
}

// ------------- L1: 1->16 conv3x3 (VALU), fp32 -> int8 NHWC, 32x32 tile -----
// MODE 1 = relu+absmax only (tracks per-co acc max; s>0 so monotone);
// MODE 2 = relu + int8 NHWC store (requant via reciprocal multiply).
template <int MODE>
__global__ __launch_bounds__(THREADS) void conv1_kernel(
    const float* __restrict__ x, const float* __restrict__ qw,
    const float* __restrict__ bias, signed char* __restrict__ out,
    unsigned int* __restrict__ slots) {
    constexpr int IH = 128, IW = 128, OH = 126, OW = 126;
    __shared__ float tile[34 * 34];
    __shared__ float wred[4];
    const int bid = xcd_swz(blockIdx.x, gridDim.x);
    const int n = bid >> 4, tr = bid & 15;
    const int oy0 = (tr >> 2) * 32, ox0 = (tr & 3) * 32;
    const float s_in = fmaxf(__uint_as_float(slots[0]), 1e-8f) / 127.0f;
    const float* xN = x + (size_t)n * IH * IW;

#pragma unroll
    for (int it = 0; it < 5; ++it) {
        int px = it * 256 + threadIdx.x;
        if (px < 1156) {
            int iy = px / 34, ix = px - iy * 34;
            int gy = min(oy0 + iy, IH - 1), gx = min(ox0 + ix, IW - 1);
            float q = rintf(xN[gy * IW + gx] / s_in);  // exact div, as reference
            tile[px] = fminf(fmaxf(q, -128.f), 127.f);
        }
    }
    __syncthreads();

    const int tx = (threadIdx.x & 15) * 2, ty = (threadIdx.x >> 4) * 2;

    // 4x4 patch -> registers once (ends 36 scalar LDS reads in the hot loop)
    float p[4][4];
#pragma unroll
    for (int r = 0; r < 4; ++r) {
        const float* rp = &tile[(ty + r) * 34 + tx];
        p[r][0] = rp[0]; p[r][1] = rp[1]; p[r][2] = rp[2]; p[r][3] = rp[3];
    }

    float r_out = 0.f;
    if constexpr (MODE == 2)
        r_out = 127.0f / fmaxf(__uint_as_float(slots[1]), 1e-8f);

    float accm[16];
#pragma unroll
    for (int c = 0; c < 16; ++c) accm[c] = -3.0e38f;

#pragma unroll
    for (int sy = 0; sy < 2; ++sy)
#pragma unroll
    for (int sx = 0; sx < 2; ++sx) {
        float acc[16];
#pragma unroll
        for (int c = 0; c < 16; ++c) acc[c] = 0.f;
#pragma unroll
        for (int ky = 0; ky < 3; ++ky)
#pragma unroll
        for (int kx = 0; kx < 3; ++kx) {
            const float xv = p[sy + ky][sx + kx];
            const float* wp = qw + (ky * 3 + kx) * 16;
#pragma unroll
            for (int co = 0; co < 16; ++co)
                acc[co] = fmaf(xv, wp[co], acc[co]);
        }
        const int oy = oy0 + ty + sy, ox = ox0 + tx + sx;
        const bool ok = (oy < OH) && (ox < OW);
        if constexpr (MODE == 1) {
            if (ok) {
#pragma unroll
                for (int co = 0; co < 16; ++co)
                    accm[co] = fmaxf(accm[co], acc[co]);
            }
        } else {
            unsigned pk[4] = {0u, 0u, 0u, 0u};
#pragma unroll
            for (int co = 0; co < 16; ++co) {
                float y = fmaxf(fmaf(acc[co], s_in, bias[co]), 0.f);
                float q8 = fminf(rintf(y * r_out), 127.f);   // y>=0
                pk[co >> 2] |= ((unsigned)(int)q8) << ((co & 3) * 8);
            }
            if (ok) {
                int4 v; v.x = pk[0]; v.y = pk[1]; v.z = pk[2]; v.w = pk[3];
                *(int4*)(out + ((size_t)(n * OH + oy) * OW + ox) * 16) = v;
            }
        }
    }
    if constexpr (MODE == 1) {
        float m = 0.f;
#pragma unroll
        for (int co = 0; co < 16; ++co)
            m = fmaxf(m, fmaxf(fmaf(accm[co], s_in, bias[co]), 0.f));
        m = block_reduce_max(m, wred);
        if (threadIdx.x == 0) atomicMax(&slots[1], __float_as_uint(m));
    }
}

// ------- L2/L3: 16->16 conv3x3, i8 MFMA 16x16x64, NHWC, 32x32 tile ---------
// Per wave: quadrant (wr,wc); 16 rows x 3 MFMAs (K=64 = 4 positions x 16ch;
// positions 9..11 zero-weight pad). B frag = one pixel's 16ch = ds_read_b128.
// LDS records XOR-swizzled (swzb) to break the stride-16B bank pattern.
template <bool STORE>
__global__ __launch_bounds__(THREADS) void mconv_kernel(
    const signed char* __restrict__ in, const signed char* __restrict__ wi8,
    const float* __restrict__ bias, signed char* __restrict__ out,
    unsigned int* __restrict__ slots, int in_slot, int w_slot, int out_slot,
    int IH, int IW) {
    __shared__ signed char tile[1156 * 16 + 128];  // +128: swizzle overshoot
    __shared__ float wred[4];
    const int OH = IH - 2, OW = IW - 2;
    const int bid = xcd_swz(blockIdx.x, gridDim.x);
    const int n = bid >> 4, tr = bid & 15;
    const int oy0 = (tr >> 2) * 32, ox0 = (tr & 3) * 32;

    const int tid = threadIdx.x, lane = tid & 63, wv = tid >> 6;
    const int q = lane >> 4, col = lane & 15;

    const signed char* inN = in + (size_t)n * IH * IW * 16;

    // staging: pure int8 copy, swizzled record address
#pragma unroll
    for (int it = 0; it < 5; ++it) {
        int px = it * 256 + tid;
        if (px < 1156) {
            int iy = px / 34, ix = px - iy * 34;
            int gy = min(oy0 + iy, IH - 1), gx = min(ox0 + ix, IW - 1);
            *(int4*)(tile + swzb(px)) =
                *(const int4*)(inN + ((size_t)gy * IW + gx) * 16);
        }
    }

    i32x4 afrag[3];
#pragma unroll
    for (int g = 0; g < 3; ++g)
        afrag[g] = ((const i32x4*)wi8)[g * 64 + lane];

    __syncthreads();

    int drec[3];
#pragma unroll
    for (int g = 0; g < 3; ++g) {
        int pos = 4 * g + q;
        int dy = (pos < 9) ? pos / 3 : 0;
        int dx = (pos < 9) ? pos % 3 : 0;   // pad reads valid px; weight = 0
        drec[g] = dy * 34 + dx;
    }
    const int wr = wv >> 1, wc = wv & 1;
    const int bx = 16 * wc + col;
    const int ox = ox0 + bx;

    const float s_in = fmaxf(__uint_as_float(slots[in_slot]), 1e-8f) / 127.0f;
    const float s_w  = fmaxf(__uint_as_float(slots[w_slot]),  1e-8f) / 127.0f;
    const float sxw = s_in * s_w;
    float bj[4];
#pragma unroll
    for (int j = 0; j < 4; ++j) bj[j] = bias[q * 4 + j];
    float r_out = 0.f;
    if constexpr (STORE)
        r_out = 127.0f / fmaxf(__uint_as_float(slots[out_slot]), 1e-8f);

    signed char* outN = out + (size_t)n * OH * OW * 16;
    int mi[4];
#pragma unroll
    for (int j = 0; j < 4; ++j) mi[j] = INT_MIN;

#pragma unroll 4
    for (int r = 0; r < 16; ++r) {
        const int iy = 16 * wr + r;
        const int rec = iy * 34 + bx;
        i32x4 acc = {0, 0, 0, 0};
#pragma unroll
        for (int g = 0; g < 3; ++g) {
            i32x4 b = *(const i32x4*)(tile + swzb(rec + drec[g]));
            acc = __builtin_amdgcn_mfma_i32_16x16x64_i8(afrag[g], b, acc, 0, 0, 0);
        }
        const int oy = oy0 + iy;
        const bool ok = (oy < OH) && (ox < OW);
        if constexpr (STORE) {
            unsigned pk = 0u;
#pragma unroll
            for (int j = 0; j < 4; ++j) {
                float y = fmaxf(fmaf((float)acc[j], sxw, bj[j]), 0.f);
                float q8 = fminf(rintf(y * r_out), 127.f);   // y>=0
                pk |= ((unsigned)(int)q8) << (j * 8);
            }
            if (ok)
                *(unsigned*)(outN + ((size_t)oy * OW + ox) * 16 + q * 4) = pk;
        } else {
            // integer max per (lane,j): y = s*a+b monotone in a (s>0)
            if (ok) {
#pragma unroll
                for (int j = 0; j < 4; ++j)
                    mi[j] = (acc[j] > mi[j]) ? acc[j] : mi[j];
            }
        }
    }
    if constexpr (!STORE) {
        float m = 0.f;
#pragma unroll
        for (int j = 0; j < 4; ++j)
            m = fmaxf(m, fmaxf(fmaf((float)mi[j], sxw, bj[j]), 0.f));
        m = block_reduce_max(m, wred);
        if (tid == 0) atomicMax(&slots[out_slot], __float_as_uint(m));
    }
}

// ---------------- L4: 16->1 conv2x2 + sigmoid, NHWC in, fp32 out -----------
__global__ __launch_bounds__(THREADS) void conv4_kernel(
    const signed char* __restrict__ in, const float* __restrict__ qw,
    const float* __restrict__ bias, float* __restrict__ out,
    unsigned int* __restrict__ slots) {
    constexpr int IH = 122, IW = 122, OH = 121, OW = 121;
    const int bid = xcd_swz(blockIdx.x, gridDim.x);
    const int n = bid >> 4, tr = bid & 15;
    const int oyb = (tr >> 2) * 32 + ((threadIdx.x >> 4) * 2);
    const int oxb = (tr & 3) * 32 + ((threadIdx.x & 15) * 2);
    const float s_in = fmaxf(__uint_as_float(slots[3]), 1e-8f) / 127.0f;
    const float b0 = bias[0];
    const signed char* inN = in + (size_t)n * IH * IW * 16;

    float w[64];
#pragma unroll
    for (int i = 0; i < 64; ++i) w[i] = qw[i];  // wave-uniform -> scalar regs

#pragma unroll
    for (int sy = 0; sy < 2; ++sy)
#pragma unroll
    for (int sx = 0; sx < 2; ++sx) {
        const int oy = oyb + sy, ox = oxb + sx;
        if (oy >= OH || ox >= OW) continue;
        float acc = 0.f;
#pragma unroll
        for (int ky = 0; ky < 2; ++ky)
#pragma unroll
        for (int kx = 0; kx < 2; ++kx) {
            union { int4 v; signed char c[16]; } u;
            u.v = *(const int4*)(inN + ((size_t)(oy + ky) * IW + ox + kx) * 16);
#pragma unroll
            for (int ci = 0; ci < 16; ++ci)
                acc = fmaf((float)u.c[ci], w[(ci * 2 + ky) * 2 + kx], acc);
        }
        float y = fmaf(acc, s_in, b0);
        out[(size_t)(n * OH + oy) * OW + ox] = 1.0f / (1.0f + expf(-y));
    }
}

extern "C" void kernel_launch(void* const* d_in, const int* in_sizes, int n_in,
                              void* d_out, int out_size, void* d_ws, size_t ws_size,
                              hipStream_t stream) {
    (void)in_sizes; (void)n_in;
    const float* x  = (const float*)d_in[0];
    const float* w1 = (const float*)d_in[1];
    const float* b1 = (const float*)d_in[2];
    const float* w2 = (const float*)d_in[3];
    const float* b2 = (const float*)d_in[4];
    const float* w3 = (const float*)d_in[5];
    const float* b3 = (const float*)d_in[6];
    const float* w4 = (const float*)d_in[7];
    const float* b4 = (const float*)d_in[8];

    char* ws = (char*)d_ws;
    unsigned int* slots = (unsigned int*)ws;
    float* qw1 = (float*)(ws + 256);
    float* qw4 = (float*)(ws + 1024);
    signed char* wi8_2 = (signed char*)(ws + 2048);
    signed char* wi8_3 = (signed char*)(ws + 5120);

    const size_t Q1 = 65028096ULL;   // 256*126*126*16 int8 (h1; later h3)
    const size_t Q2 = 62980096ULL;   // 256*124*124*16 int8 (h2)
    signed char* qb1 = (signed char*)(ws + 32768);
    signed char* qb2 = (signed char*)(ws + 32768 + Q1);
    float* outp = (float*)d_out;

    const size_t need = 32768ULL + Q1 + Q2;  // ~128.06 MB
    if (ws_size < need) {
        float v = 100.0f + (float)(ws_size >> 20);
        hipLaunchKernelGGL(fill_kernel, dim3(1024), dim3(THREADS), 0, stream,
                           outp, out_size, v);
        return;
    }

    const int blocks = 256 * 16;  // 4096 = N * 16 tiles of 32x32; %8==0

    hipLaunchKernelGGL(init_kernel, dim3(1), dim3(64), 0, stream, slots);
    hipLaunchKernelGGL(absmax4_kernel, dim3(2048), dim3(THREADS), 0, stream,
                       (const float4*)x, 256 * 128 * 128 / 4, slots + 0);
    hipLaunchKernelGGL(quant_w_kernel, dim3(4), dim3(THREADS), 0, stream,
                       w1, w2, w3, w4, qw1, qw4, wi8_2, wi8_3, slots);

    // L1: fp32 x -> int8 h1 (NHWC), two passes
    hipLaunchKernelGGL((conv1_kernel<1>), dim3(blocks), dim3(THREADS), 0, stream,
                       x, qw1, b1, nullptr, slots);
    hipLaunchKernelGGL((conv1_kernel<2>), dim3(blocks), dim3(THREADS), 0, stream,
                       x, qw1, b1, qb1, slots);
    // L2 (i8 MFMA): h1 -> h2, two passes
    hipLaunchKernelGGL((mconv_kernel<false>), dim3(blocks), dim3(THREADS), 0, stream,
                       qb1, wi8_2, b2, nullptr, slots, 1, 5, 2, 126, 126);
    hipLaunchKernelGGL((mconv_kernel<true>), dim3(blocks), dim3(THREADS), 0, stream,
                       qb1, wi8_2, b2, qb2, slots, 1, 5, 2, 126, 126);
    // L3 (i8 MFMA): h2 -> h3 (reuses qb1), two passes
    hipLaunchKernelGGL((mconv_kernel<false>), dim3(blocks), dim3(THREADS), 0, stream,
                       qb2, wi8_3, b3, nullptr, slots, 2, 6, 3, 124, 124);
    hipLaunchKernelGGL((mconv_kernel<true>), dim3(blocks), dim3(THREADS), 0, stream,
                       qb2, wi8_3, b3, qb1, slots, 2, 6, 3, 124, 124);
    // L4: h3 -> fp32 out, sigmoid, single pass
    hipLaunchKernelGGL(conv4_kernel, dim3(blocks), dim3(THREADS), 0, stream,
                       qb1, qw4, b4, outp, slots);
}